// Round 16
// baseline (190.105 us; speedup 1.0000x reference)
//
#include <hip/hip_runtime.h>
#include <math.h>
#include <limits.h>

// VQVAE: N=262144, K=1024, D=64. Outputs flat fp32: Z[N], q_with_st[N*64], 2 losses.
// R16 = R15 (fp16 2-term MFMA, BIGC-in-init, u32 keys) + two changes:
//  (1) vq: 8 chunks of 128 codes (was 16x64) -> half the barrier drains.
//      LDS 2x16KB + 4KB = 36KB, still 4 blocks/CU.
//  (2) rescore: 16 rows/block (R11-structure, correctness-proven) with
//      STREAMED cv + manual next-quad prefetch (no cv[16] array -> no R11/R12
//      spill; 2 loads in flight hides L2 latency of the serial q-loop).
// prep/epilogue/finalize: byte-identical to R13-R15 (absmax 0 proven).

static constexpr int NROWS = 262144;
static constexpr int KC    = 1024;
static constexpr int DIM   = 64;
static constexpr int CAP   = 65536;

// d_ws layout (bytes); ws >= 565256 proven in rounds 4-6.
static constexpr size_t CSQ_OFF    = 0;          // 1024 f32
static constexpr size_t CSPRE_OFF  = 4096;       // 1024 f32 (= 65536*csq + BIGC)
static constexpr size_t CSPLIT_OFF = 8192;       // 128 KB fp16 -> ends 139264
static constexpr size_t CTR_OFF    = 139264;     // 1 int
static constexpr size_t LIST_OFF   = 139268;     // CAP ints -> ends 401412
static constexpr size_t PART_OFF   = 401416;     // 4096 doubles -> ends 434184

static constexpr float BIGC = 83886080.0f;       // 5 * 2^24

typedef __attribute__((ext_vector_type(8)))  _Float16 half8;
typedef __attribute__((ext_vector_type(16))) float    f32x16;

static __device__ __forceinline__ unsigned umin(unsigned a, unsigned b) { return a < b ? a : b; }
static __device__ __forceinline__ unsigned umax(unsigned a, unsigned b) { return a > b ? a : b; }

// ------------------------------------------------ prep
// csplit (fp16) ushort index = sub*4096 + slot*512 + c_l*8 + e ; sub=c>>6,
// c_l=c&63, slot=d>>3, e=d&7. Values = fp16(c * -2^17). A 128-code chunk is
// two consecutive subs (contiguous 8 KB + 8 KB).
__global__ __launch_bounds__(64) void prep_kernel(const float* __restrict__ cb,
                                                  float* __restrict__ csq,
                                                  float* __restrict__ cspre,
                                                  unsigned short* __restrict__ cs,
                                                  float4* __restrict__ cbt4,
                                                  int* __restrict__ counter) {
#pragma clang fp contract(off)
    if (blockIdx.x == 0 && threadIdx.x == 0) *counter = 0;
    const int c = blockIdx.x * 64 + threadIdx.x;
    const float4* row = reinterpret_cast<const float4*>(cb + (size_t)c * DIM);
    float e[64];
#pragma unroll
    for (int q = 0; q < 16; ++q) {
        float4 v = row[q];
        cbt4[q * 1024 + c] = v;                         // transposed copy (coalesced)
        e[q * 4 + 0] = v.x; e[q * 4 + 1] = v.y;
        e[q * 4 + 2] = v.z; e[q * 4 + 3] = v.w;
    }
    float r[8];
#pragma unroll
    for (int g = 0; g < 8; ++g)
#pragma unroll
        for (int j = 0; j < 8; ++j) {
            float sq = e[8 * g + j] * e[8 * g + j];     // rounded square (no fma)
            if (g == 0) r[j] = sq; else r[j] += sq;
        }
    float s = ((r[0] + r[1]) + (r[2] + r[3])) + ((r[4] + r[5]) + (r[6] + r[7]));
    csq[c]   = s;
    cspre[c] = 65536.0f * s + BIGC;                     // one rounding (<=0.5 ulp(2^26))

    const int sub = c >> 6, c_l = c & 63;
    unsigned short* base = cs + (size_t)sub * 4096 + (size_t)c_l * 8;
#pragma unroll
    for (int g = 0; g < 8; ++g) {
        half8 hv;
#pragma unroll
        for (int j = 0; j < 8; ++j)
            hv[j] = (_Float16)(e[8 * g + j] * -131072.0f);   // fp16 RTN
        *reinterpret_cast<half8*>(base + g * 512) = hv;
    }
}

// ------------------------------------------------ MFMA distance + packed-key argmin
// 8 chunks x 16 KB fp16 (128 codes); double-buffered global_load_lds
// (4 iters x 1 KB per wave).
#define STAGE(buf_, chk_) do {                                                          \
    const char* _s = (const char*)csplit + (size_t)(chk_) * 16384                       \
                     + (size_t)w * 4096 + (size_t)lane * 16;                            \
    char* _d = (char*)(&bbuf[buf_][0]) + (size_t)w * 4096;                              \
    _Pragma("unroll")                                                                   \
    for (int _it = 0; _it < 4; ++_it)                                                   \
        __builtin_amdgcn_global_load_lds(                                               \
            (const __attribute__((address_space(1))) unsigned int*)(_s + _it * 1024),   \
            (__attribute__((address_space(3))) unsigned int*)(_d + _it * 1024),         \
            16, 0, 0);                                                                  \
} while (0)

__global__ __launch_bounds__(256, 4) void vq_mfma_kernel(
        const float* __restrict__ x, const unsigned short* __restrict__ csplit,
        const float* __restrict__ cspre_g, float* __restrict__ zout,
        int* __restrict__ counter, int* __restrict__ list) {
    __shared__ unsigned short bbuf[2][8192];   // 2 x 16 KB
    __shared__ float cspre_s[1024];            // 4 KB

    const int tid  = threadIdx.x;
    const int w    = tid >> 6;
    const int lane = tid & 63;
    const int h    = lane >> 5;
    const int cl5  = lane & 31;
    const int rowbase = blockIdx.x * 256 + w * 64;

    STAGE(0, 0);
    {   // cspre -> LDS
        float4 v = reinterpret_cast<const float4*>(cspre_g)[tid];
        reinterpret_cast<float4*>(cspre_s)[tid] = v;
    }

    // x fragments (B-operand): fp16 hi/lo split in registers.
    half8 xh[2][4], xl[2][4];
    float sa[2];
#pragma unroll
    for (int R = 0; R < 2; ++R) {
        const float* xrow = x + (size_t)(rowbase + R * 32 + cl5) * DIM;
        float s = 0.0f;
#pragma unroll
        for (int j = 0; j < 4; ++j) {
            float4 p0 = *reinterpret_cast<const float4*>(xrow + j * 16 + h * 8);
            float4 p1 = *reinterpret_cast<const float4*>(xrow + j * 16 + h * 8 + 4);
            float v[8] = {p0.x, p0.y, p0.z, p0.w, p1.x, p1.y, p1.z, p1.w};
#pragma unroll
            for (int e = 0; e < 8; ++e) {
                float f = v[e];
                s += fabsf(f);
                _Float16 hx = (_Float16)f;              // RTN
                float fh = (float)hx;                   // exact
                xh[R][j][e] = hx;
                xl[R][j][e] = (_Float16)(f - fh);
            }
        }
        s += __shfl_xor(s, 32, 64);            // complementary d-half, same row
        sa[R] = s;
    }
    __syncthreads();                           // chunk0 + cspre ready

    unsigned k1[2] = {0xFFFFFFFFu, 0xFFFFFFFFu};
    unsigned k2[2] = {0xFFFFFFFFu, 0xFFFFFFFFu};
    const int lofs = cl5 * 16 + h * 1024;
    static constexpr int IDX[16] = {0,1,2,3, 8,9,10,11, 16,17,18,19, 24,25,26,27};

    for (int chk = 0; chk < 8; ++chk) {
        const int cur = chk & 1;
        if (chk < 7) STAGE(cur ^ 1, chk + 1);
        const char* bb = (const char*)(&bbuf[cur][0]);
#pragma unroll
        for (int t = 0; t < 4; ++t) {          // 4 tiles of 32 codes
            const unsigned cbase = (unsigned)(chk * 128 + t * 32 + 4 * h);
            const float* cp = &cspre_s[chk * 128 + t * 32 + 4 * h];
            float4 g0 = *reinterpret_cast<const float4*>(cp);
            float4 g1 = *reinterpret_cast<const float4*>(cp + 8);
            float4 g2 = *reinterpret_cast<const float4*>(cp + 16);
            float4 g3 = *reinterpret_cast<const float4*>(cp + 24);
            f32x16 ini;
            ini[0]  = g0.x; ini[1]  = g0.y; ini[2]  = g0.z; ini[3]  = g0.w;
            ini[4]  = g1.x; ini[5]  = g1.y; ini[6]  = g1.z; ini[7]  = g1.w;
            ini[8]  = g2.x; ini[9]  = g2.y; ini[10] = g2.z; ini[11] = g2.w;
            ini[12] = g3.x; ini[13] = g3.y; ini[14] = g3.z; ini[15] = g3.w;

            // sub-chunk (t>>1)*8KB, code base (t&1)*512B, slot 2j+h.
            const char* bp = bb + (t >> 1) * 8192 + (t & 1) * 512 + lofs;
            f32x16 a0, a1;
            {   // j = 0: ini is shared read-only C for both acc chains
                half8 bch = *reinterpret_cast<const half8*>(bp);
                a0 = __builtin_amdgcn_mfma_f32_32x32x16_f16(bch, xh[0][0], ini, 0, 0, 0);
                a1 = __builtin_amdgcn_mfma_f32_32x32x16_f16(bch, xh[1][0], ini, 0, 0, 0);
                a0 = __builtin_amdgcn_mfma_f32_32x32x16_f16(bch, xl[0][0], a0, 0, 0, 0);
                a1 = __builtin_amdgcn_mfma_f32_32x32x16_f16(bch, xl[1][0], a1, 0, 0, 0);
            }
#pragma unroll
            for (int j = 1; j < 4; ++j) {
                half8 bch = *reinterpret_cast<const half8*>(bp + j * 2048);
                a0 = __builtin_amdgcn_mfma_f32_32x32x16_f16(bch, xh[0][j], a0, 0, 0, 0);
                a1 = __builtin_amdgcn_mfma_f32_32x32x16_f16(bch, xh[1][j], a1, 0, 0, 0);
                a0 = __builtin_amdgcn_mfma_f32_32x32x16_f16(bch, xl[0][j], a0, 0, 0, 0);
                a1 = __builtin_amdgcn_mfma_f32_32x32x16_f16(bch, xl[1][j], a1, 0, 0, 0);
            }
            // acc = BIGC + 65536*(csq - 2*dot) (BIGC in C-init);
            // key = (bits(acc)<<10)+code : u32-monotone (const exponent, bit22=0).
#pragma unroll
            for (int p = 0; p < 8; ++p) {
                const int r = 2 * p, r2 = 2 * p + 1;
                {
                    unsigned ka = (__float_as_uint(a0[r])  << 10) + cbase + IDX[r];
                    unsigned kb = (__float_as_uint(a0[r2]) << 10) + cbase + IDX[r2];
                    unsigned pmin = umin(ka, kb), pmax = umax(ka, kb);
                    unsigned tt = umax(pmin, k1[0]);
                    k2[0] = umin(umin(k2[0], tt), pmax);   // v_min3
                    k1[0] = umin(k1[0], pmin);
                }
                {
                    unsigned ka = (__float_as_uint(a1[r])  << 10) + cbase + IDX[r];
                    unsigned kb = (__float_as_uint(a1[r2]) << 10) + cbase + IDX[r2];
                    unsigned pmin = umin(ka, kb), pmax = umax(ka, kb);
                    unsigned tt = umax(pmin, k1[1]);
                    k2[1] = umin(umin(k2[1], tt), pmax);
                    k1[1] = umin(k1[1], pmin);
                }
            }
        }
        __syncthreads();           // my reads done; staged chunk landed
    }

    // merge complementary code-subsets (lane <-> lane^32)
    unsigned K1[2], K2[2];
#pragma unroll
    for (int R = 0; R < 2; ++R) {
        unsigned o1 = (unsigned)__shfl_xor((int)k1[R], 32, 64);
        unsigned o2 = (unsigned)__shfl_xor((int)k2[R], 32, 64);
        unsigned mn = umin(k1[R], o1), mx = umax(k1[R], o1);
        K1[R] = mn;
        K2[R] = umin(umin(k2[R], o2), mx);
    }
    {
        const unsigned bk1 = h ? K1[1] : K1[0];
        const unsigned bk2 = h ? K2[1] : K2[0];
        const float    SA  = h ? sa[1] : sa[0];
        const int row = rowbase + h * 32 + cl5;
        zout[row] = (float)(bk1 & 1023u);
        // T = 1.2e-4*SA + 1.4e-3 (R15-validated); key quantum 1.22e-4.
        unsigned Tq = (unsigned)(8192.0f * (1.2e-4f * SA + 1.4e-3f)) + 2u;
        if ((bk2 - bk1) < (Tq << 10)) {
            int id = atomicAdd(counter, 1);
            if (id < CAP) list[id] = row;
        }
    }
}

// ---------------------------------------------------------------- exact rescore (bitwise ref)
// R16: 16 rows/block (R11 structure), cv STREAMED with manual next-quad
// prefetch — exactly two codebook quads live (no array -> no spill). q/cc
// loops unroll-disabled. FMA chain (q ascending, x/y/z/w) bitwise-identical
// to the verified body (rounds 1/3/4/5/6/8-15).
__global__ __launch_bounds__(256) void rescore_kernel(
        const float* __restrict__ x, const float4* __restrict__ cbt4,
        const float* __restrict__ csq, const int* __restrict__ counter,
        const int* __restrict__ list, float* __restrict__ zout) {
#pragma clang fp contract(off)
    __shared__ float xs[16][64];
    __shared__ float xsq_s[16];
    __shared__ float bv[4][16];
    __shared__ int   bix[4][16];
    const int tid  = threadIdx.x;
    const int lane = tid & 63;
    const int w    = tid >> 6;
    int cnt = *counter; if (cnt > CAP) cnt = CAP;

    for (int base = blockIdx.x * 16; base < cnt; base += gridDim.x * 16) {
        {   // stage 16 rows (tail-clamped; dup slots computed, not written)
            int r  = tid >> 4, q = tid & 15;
            int li = base + r; if (li >= cnt) li = cnt - 1;
            int row = list[li];
            float4 v = reinterpret_cast<const float4*>(x + (size_t)row * DIM)[q];
            *reinterpret_cast<float4*>(&xs[r][q * 4]) = v;
        }
        __syncthreads();
        if (tid < 16) {   // x_sq: numpy pairwise structure (bitwise-same values)
            float r8[8];
#pragma unroll
            for (int g = 0; g < 8; ++g)
#pragma unroll
                for (int j = 0; j < 8; ++j) {
                    float xv = xs[tid][8 * g + j];
                    float sq = xv * xv;
                    if (g == 0) r8[j] = sq; else r8[j] += sq;
                }
            xsq_s[tid] = ((r8[0] + r8[1]) + (r8[2] + r8[3]))
                       + ((r8[4] + r8[5]) + (r8[6] + r8[7]));
        }
        __syncthreads();

        float bmv[16]; int bmi[16];
#pragma unroll
        for (int r = 0; r < 16; ++r) { bmv[r] = INFINITY; bmi[r] = 0; }

#pragma clang loop unroll(disable)
        for (int cc = 0; cc < 4; ++cc) {
            const int c = cc * 256 + tid;             // in-thread ascending
            float dot[16];
#pragma unroll
            for (int r = 0; r < 16; ++r) dot[r] = 0.0f;
            float4 cv = cbt4[c];                      // q = 0 quad
#pragma clang loop unroll(disable)
            for (int q = 0; q < 16; ++q) {
                const int qn = (q < 15) ? q + 1 : 15;
                float4 nv = cbt4[qn * 1024 + c];      // prefetch next quad
#pragma unroll
                for (int r = 0; r < 16; ++r) {
                    float4 xv = *reinterpret_cast<const float4*>(&xs[r][q * 4]);
                    dot[r] = __builtin_fmaf(cv.x, xv.x, dot[r]);
                    dot[r] = __builtin_fmaf(cv.y, xv.y, dot[r]);
                    dot[r] = __builtin_fmaf(cv.z, xv.z, dot[r]);
                    dot[r] = __builtin_fmaf(cv.w, xv.w, dot[r]);
                }
                cv = nv;
            }
            const float cs = csq[c];
#pragma unroll
            for (int r = 0; r < 16; ++r) {
                float dist = (xsq_s[r] - 2.0f * dot[r]) + cs;
                if (dist < bmv[r]) { bmv[r] = dist; bmi[r] = c; }
            }
        }

        // per-row reduce: wave lex-min, then cross-wave via LDS
#pragma unroll
        for (int r = 0; r < 16; ++r) {
#pragma unroll
            for (int m = 1; m <= 32; m <<= 1) {
                float ov = __shfl_xor(bmv[r], m, 64);
                int   oi = __shfl_xor(bmi[r], m, 64);
                if (ov < bmv[r] || (ov == bmv[r] && oi < bmi[r])) {
                    bmv[r] = ov; bmi[r] = oi;
                }
            }
            if (lane == 0) { bv[w][r] = bmv[r]; bix[w][r] = bmi[r]; }
        }
        __syncthreads();
        if (tid < 16) {
            float v = bv[0][tid]; int ix = bix[0][tid];
#pragma unroll
            for (int k = 1; k < 4; ++k)
                if (bv[k][tid] < v || (bv[k][tid] == v && bix[k][tid] < ix)) {
                    v = bv[k][tid]; ix = bix[k][tid];
                }
            int li = base + tid;
            if (li < cnt) zout[list[li]] = (float)ix;
        }
        __syncthreads();   // xs/bv reused next batch
    }
}

// ---------------------------------------------------------------- epilogue
__global__ __launch_bounds__(256) void epilogue_kernel(
        const float* __restrict__ x, const float* __restrict__ cb,
        const float* __restrict__ zf, float* __restrict__ qout,
        double* __restrict__ partial) {
#pragma clang fp contract(off)
    const int gid = blockIdx.x * 256 + threadIdx.x;
    const int row = gid >> 2;
    const int d0  = (gid & 3) * 16;
    const float4* xr = reinterpret_cast<const float4*>(x + (size_t)row * DIM + d0);
    const int z = (int)zf[row];
    const float4* qr = reinterpret_cast<const float4*>(cb + (size_t)z * DIM + d0);
    float4* op = reinterpret_cast<float4*>(qout + (size_t)row * DIM + d0);

    float lf = 0.0f;
#pragma unroll
    for (int q = 0; q < 4; ++q) {
        float4 xv = xr[q];
        float4 qv = qr[q];
        float da = qv.x - xv.x, db = qv.y - xv.y, dc = qv.z - xv.z, dd = qv.w - xv.w;
        float4 o;
        o.x = xv.x + da; o.y = xv.y + db; o.z = xv.z + dc; o.w = xv.w + dd;
        op[q] = o;
        lf += da * da; lf += db * db; lf += dc * dc; lf += dd * dd;
    }
    double lsum = (double)lf;
#pragma unroll
    for (int s = 32; s >= 1; s >>= 1) lsum += __shfl_down(lsum, s, 64);
    __shared__ double wsum[4];
    const int lane = threadIdx.x & 63, wid = threadIdx.x >> 6;
    if (lane == 0) wsum[wid] = lsum;
    __syncthreads();
    if (threadIdx.x == 0)
        partial[blockIdx.x] = (wsum[0] + wsum[1]) + (wsum[2] + wsum[3]);
}

__global__ void finalize_kernel(const double* __restrict__ partial,
                                float* __restrict__ losses) {
    double s = 0.0;
    int lane = threadIdx.x;
    for (int i = lane; i < 4096; i += 64) s += partial[i];
#pragma unroll
    for (int sh = 32; sh >= 1; sh >>= 1) s += __shfl_down(s, sh, 64);
    if (lane == 0) {
        float v = (float)(s / 16777216.0);
        losses[0] = v;
        losses[1] = v;
    }
}

extern "C" void kernel_launch(void* const* d_in, const int* in_sizes, int n_in,
                              void* d_out, int out_size, void* d_ws, size_t ws_size,
                              hipStream_t stream) {
    const float* x  = (const float*)d_in[0];
    const float* cb = (const float*)d_in[1];
    float* out    = (float*)d_out;
    float* zout   = out;
    float* qout   = out + NROWS;
    float* losses = out + NROWS + (size_t)NROWS * DIM;

    float*          csq     = (float*)((char*)d_ws + CSQ_OFF);
    float*          cspre   = (float*)((char*)d_ws + CSPRE_OFF);
    unsigned short* csplit  = (unsigned short*)((char*)d_ws + CSPLIT_OFF);
    int*            counter = (int*)((char*)d_ws + CTR_OFF);
    int*            list    = (int*)((char*)d_ws + LIST_OFF);
    double*         partial = (double*)((char*)d_ws + PART_OFF);

    // cbT4 (256 KB) lives in the qout region of d_out: written by prep, read by
    // rescore, fully overwritten by the epilogue afterwards (R6-proven).
    float4* cbt4 = (float4*)qout;

    prep_kernel<<<16, 64, 0, stream>>>(cb, csq, cspre, csplit, cbt4, counter);
    vq_mfma_kernel<<<NROWS / 256, 256, 0, stream>>>(x, csplit, cspre, zout, counter, list);
    rescore_kernel<<<1024, 256, 0, stream>>>(x, cbt4, csq, counter, list, zout);
    epilogue_kernel<<<(NROWS * 4) / 256, 256, 0, stream>>>(x, cb, zout, qout, partial);
    finalize_kernel<<<1, 64, 0, stream>>>(partial, losses);
}

// Round 17
// 169.424 us; speedup vs baseline: 1.1221x; 1.1221x over previous
//
#include <hip/hip_runtime.h>
#include <math.h>
#include <limits.h>

// VQVAE: N=262144, K=1024, D=64. Outputs flat fp32: Z[N], q_with_st[N*64], 2 losses.
// R17 = R16's vq (fp16 2-term MFMA, BIGC-in-init, u32 keys, 8 chunks x 128
// codes) + R13/R15's rescore RESTORED VERBATIM (8 rows/block, unroll-disabled
// streaming — best measured at ~38us; R16's 16-row+prefetch variant cost +25us).
// prep/epilogue/finalize: byte-identical to R13-R16 (absmax 0 proven).

static constexpr int NROWS = 262144;
static constexpr int KC    = 1024;
static constexpr int DIM   = 64;
static constexpr int CAP   = 65536;

// d_ws layout (bytes); ws >= 565256 proven in rounds 4-6.
static constexpr size_t CSQ_OFF    = 0;          // 1024 f32
static constexpr size_t CSPRE_OFF  = 4096;       // 1024 f32 (= 65536*csq + BIGC)
static constexpr size_t CSPLIT_OFF = 8192;       // 128 KB fp16 -> ends 139264
static constexpr size_t CTR_OFF    = 139264;     // 1 int
static constexpr size_t LIST_OFF   = 139268;     // CAP ints -> ends 401412
static constexpr size_t PART_OFF   = 401416;     // 4096 doubles -> ends 434184

static constexpr float BIGC = 83886080.0f;       // 5 * 2^24

typedef __attribute__((ext_vector_type(8)))  _Float16 half8;
typedef __attribute__((ext_vector_type(16))) float    f32x16;

static __device__ __forceinline__ unsigned umin(unsigned a, unsigned b) { return a < b ? a : b; }
static __device__ __forceinline__ unsigned umax(unsigned a, unsigned b) { return a > b ? a : b; }

// ------------------------------------------------ prep
// csplit (fp16) ushort index = sub*4096 + slot*512 + c_l*8 + e ; sub=c>>6,
// c_l=c&63, slot=d>>3, e=d&7. Values = fp16(c * -2^17). A 128-code chunk is
// two consecutive subs (contiguous 8 KB + 8 KB).
__global__ __launch_bounds__(64) void prep_kernel(const float* __restrict__ cb,
                                                  float* __restrict__ csq,
                                                  float* __restrict__ cspre,
                                                  unsigned short* __restrict__ cs,
                                                  float4* __restrict__ cbt4,
                                                  int* __restrict__ counter) {
#pragma clang fp contract(off)
    if (blockIdx.x == 0 && threadIdx.x == 0) *counter = 0;
    const int c = blockIdx.x * 64 + threadIdx.x;
    const float4* row = reinterpret_cast<const float4*>(cb + (size_t)c * DIM);
    float e[64];
#pragma unroll
    for (int q = 0; q < 16; ++q) {
        float4 v = row[q];
        cbt4[q * 1024 + c] = v;                         // transposed copy (coalesced)
        e[q * 4 + 0] = v.x; e[q * 4 + 1] = v.y;
        e[q * 4 + 2] = v.z; e[q * 4 + 3] = v.w;
    }
    float r[8];
#pragma unroll
    for (int g = 0; g < 8; ++g)
#pragma unroll
        for (int j = 0; j < 8; ++j) {
            float sq = e[8 * g + j] * e[8 * g + j];     // rounded square (no fma)
            if (g == 0) r[j] = sq; else r[j] += sq;
        }
    float s = ((r[0] + r[1]) + (r[2] + r[3])) + ((r[4] + r[5]) + (r[6] + r[7]));
    csq[c]   = s;
    cspre[c] = 65536.0f * s + BIGC;                     // one rounding (<=0.5 ulp(2^26))

    const int sub = c >> 6, c_l = c & 63;
    unsigned short* base = cs + (size_t)sub * 4096 + (size_t)c_l * 8;
#pragma unroll
    for (int g = 0; g < 8; ++g) {
        half8 hv;
#pragma unroll
        for (int j = 0; j < 8; ++j)
            hv[j] = (_Float16)(e[8 * g + j] * -131072.0f);   // fp16 RTN
        *reinterpret_cast<half8*>(base + g * 512) = hv;
    }
}

// ------------------------------------------------ MFMA distance + packed-key argmin
// 8 chunks x 16 KB fp16 (128 codes); double-buffered global_load_lds
// (4 iters x 1 KB per wave).
#define STAGE(buf_, chk_) do {                                                          \
    const char* _s = (const char*)csplit + (size_t)(chk_) * 16384                       \
                     + (size_t)w * 4096 + (size_t)lane * 16;                            \
    char* _d = (char*)(&bbuf[buf_][0]) + (size_t)w * 4096;                              \
    _Pragma("unroll")                                                                   \
    for (int _it = 0; _it < 4; ++_it)                                                   \
        __builtin_amdgcn_global_load_lds(                                               \
            (const __attribute__((address_space(1))) unsigned int*)(_s + _it * 1024),   \
            (__attribute__((address_space(3))) unsigned int*)(_d + _it * 1024),         \
            16, 0, 0);                                                                  \
} while (0)

__global__ __launch_bounds__(256, 4) void vq_mfma_kernel(
        const float* __restrict__ x, const unsigned short* __restrict__ csplit,
        const float* __restrict__ cspre_g, float* __restrict__ zout,
        int* __restrict__ counter, int* __restrict__ list) {
    __shared__ unsigned short bbuf[2][8192];   // 2 x 16 KB
    __shared__ float cspre_s[1024];            // 4 KB

    const int tid  = threadIdx.x;
    const int w    = tid >> 6;
    const int lane = tid & 63;
    const int h    = lane >> 5;
    const int cl5  = lane & 31;
    const int rowbase = blockIdx.x * 256 + w * 64;

    STAGE(0, 0);
    {   // cspre -> LDS
        float4 v = reinterpret_cast<const float4*>(cspre_g)[tid];
        reinterpret_cast<float4*>(cspre_s)[tid] = v;
    }

    // x fragments (B-operand): fp16 hi/lo split in registers.
    half8 xh[2][4], xl[2][4];
    float sa[2];
#pragma unroll
    for (int R = 0; R < 2; ++R) {
        const float* xrow = x + (size_t)(rowbase + R * 32 + cl5) * DIM;
        float s = 0.0f;
#pragma unroll
        for (int j = 0; j < 4; ++j) {
            float4 p0 = *reinterpret_cast<const float4*>(xrow + j * 16 + h * 8);
            float4 p1 = *reinterpret_cast<const float4*>(xrow + j * 16 + h * 8 + 4);
            float v[8] = {p0.x, p0.y, p0.z, p0.w, p1.x, p1.y, p1.z, p1.w};
#pragma unroll
            for (int e = 0; e < 8; ++e) {
                float f = v[e];
                s += fabsf(f);
                _Float16 hx = (_Float16)f;              // RTN
                float fh = (float)hx;                   // exact
                xh[R][j][e] = hx;
                xl[R][j][e] = (_Float16)(f - fh);
            }
        }
        s += __shfl_xor(s, 32, 64);            // complementary d-half, same row
        sa[R] = s;
    }
    __syncthreads();                           // chunk0 + cspre ready

    unsigned k1[2] = {0xFFFFFFFFu, 0xFFFFFFFFu};
    unsigned k2[2] = {0xFFFFFFFFu, 0xFFFFFFFFu};
    const int lofs = cl5 * 16 + h * 1024;
    static constexpr int IDX[16] = {0,1,2,3, 8,9,10,11, 16,17,18,19, 24,25,26,27};

    for (int chk = 0; chk < 8; ++chk) {
        const int cur = chk & 1;
        if (chk < 7) STAGE(cur ^ 1, chk + 1);
        const char* bb = (const char*)(&bbuf[cur][0]);
#pragma unroll
        for (int t = 0; t < 4; ++t) {          // 4 tiles of 32 codes
            const unsigned cbase = (unsigned)(chk * 128 + t * 32 + 4 * h);
            const float* cp = &cspre_s[chk * 128 + t * 32 + 4 * h];
            float4 g0 = *reinterpret_cast<const float4*>(cp);
            float4 g1 = *reinterpret_cast<const float4*>(cp + 8);
            float4 g2 = *reinterpret_cast<const float4*>(cp + 16);
            float4 g3 = *reinterpret_cast<const float4*>(cp + 24);
            f32x16 ini;
            ini[0]  = g0.x; ini[1]  = g0.y; ini[2]  = g0.z; ini[3]  = g0.w;
            ini[4]  = g1.x; ini[5]  = g1.y; ini[6]  = g1.z; ini[7]  = g1.w;
            ini[8]  = g2.x; ini[9]  = g2.y; ini[10] = g2.z; ini[11] = g2.w;
            ini[12] = g3.x; ini[13] = g3.y; ini[14] = g3.z; ini[15] = g3.w;

            // sub-chunk (t>>1)*8KB, code base (t&1)*512B, slot 2j+h.
            const char* bp = bb + (t >> 1) * 8192 + (t & 1) * 512 + lofs;
            f32x16 a0, a1;
            {   // j = 0: ini is shared read-only C for both acc chains
                half8 bch = *reinterpret_cast<const half8*>(bp);
                a0 = __builtin_amdgcn_mfma_f32_32x32x16_f16(bch, xh[0][0], ini, 0, 0, 0);
                a1 = __builtin_amdgcn_mfma_f32_32x32x16_f16(bch, xh[1][0], ini, 0, 0, 0);
                a0 = __builtin_amdgcn_mfma_f32_32x32x16_f16(bch, xl[0][0], a0, 0, 0, 0);
                a1 = __builtin_amdgcn_mfma_f32_32x32x16_f16(bch, xl[1][0], a1, 0, 0, 0);
            }
#pragma unroll
            for (int j = 1; j < 4; ++j) {
                half8 bch = *reinterpret_cast<const half8*>(bp + j * 2048);
                a0 = __builtin_amdgcn_mfma_f32_32x32x16_f16(bch, xh[0][j], a0, 0, 0, 0);
                a1 = __builtin_amdgcn_mfma_f32_32x32x16_f16(bch, xh[1][j], a1, 0, 0, 0);
                a0 = __builtin_amdgcn_mfma_f32_32x32x16_f16(bch, xl[0][j], a0, 0, 0, 0);
                a1 = __builtin_amdgcn_mfma_f32_32x32x16_f16(bch, xl[1][j], a1, 0, 0, 0);
            }
            // acc = BIGC + 65536*(csq - 2*dot) (BIGC in C-init);
            // key = (bits(acc)<<10)+code : u32-monotone (const exponent, bit22=0).
#pragma unroll
            for (int p = 0; p < 8; ++p) {
                const int r = 2 * p, r2 = 2 * p + 1;
                {
                    unsigned ka = (__float_as_uint(a0[r])  << 10) + cbase + IDX[r];
                    unsigned kb = (__float_as_uint(a0[r2]) << 10) + cbase + IDX[r2];
                    unsigned pmin = umin(ka, kb), pmax = umax(ka, kb);
                    unsigned tt = umax(pmin, k1[0]);
                    k2[0] = umin(umin(k2[0], tt), pmax);   // v_min3
                    k1[0] = umin(k1[0], pmin);
                }
                {
                    unsigned ka = (__float_as_uint(a1[r])  << 10) + cbase + IDX[r];
                    unsigned kb = (__float_as_uint(a1[r2]) << 10) + cbase + IDX[r2];
                    unsigned pmin = umin(ka, kb), pmax = umax(ka, kb);
                    unsigned tt = umax(pmin, k1[1]);
                    k2[1] = umin(umin(k2[1], tt), pmax);
                    k1[1] = umin(k1[1], pmin);
                }
            }
        }
        __syncthreads();           // my reads done; staged chunk landed
    }

    // merge complementary code-subsets (lane <-> lane^32)
    unsigned K1[2], K2[2];
#pragma unroll
    for (int R = 0; R < 2; ++R) {
        unsigned o1 = (unsigned)__shfl_xor((int)k1[R], 32, 64);
        unsigned o2 = (unsigned)__shfl_xor((int)k2[R], 32, 64);
        unsigned mn = umin(k1[R], o1), mx = umax(k1[R], o1);
        K1[R] = mn;
        K2[R] = umin(umin(k2[R], o2), mx);
    }
    {
        const unsigned bk1 = h ? K1[1] : K1[0];
        const unsigned bk2 = h ? K2[1] : K2[0];
        const float    SA  = h ? sa[1] : sa[0];
        const int row = rowbase + h * 32 + cl5;
        zout[row] = (float)(bk1 & 1023u);
        // T = 1.2e-4*SA + 1.4e-3 (R15-validated); key quantum 1.22e-4.
        unsigned Tq = (unsigned)(8192.0f * (1.2e-4f * SA + 1.4e-3f)) + 2u;
        if ((bk2 - bk1) < (Tq << 10)) {
            int id = atomicAdd(counter, 1);
            if (id < CAP) list[id] = row;
        }
    }
}

// ---------------------------------------------------------------- exact rescore (bitwise ref)
// R13/R15-proven VERBATIM: 8 rows/block, q/cc loops unroll-DISABLED
// (anti-hoisting, no spill). ~38us measured.
__global__ __launch_bounds__(256) void rescore_kernel(
        const float* __restrict__ x, const float4* __restrict__ cbt4,
        const float* __restrict__ csq, const int* __restrict__ counter,
        const int* __restrict__ list, float* __restrict__ zout) {
#pragma clang fp contract(off)
    __shared__ float xs[8][64];
    __shared__ float xsq_s[8];
    __shared__ float bv[4][8];
    __shared__ int   bix[4][8];
    const int tid  = threadIdx.x;
    const int lane = tid & 63;
    const int w    = tid >> 6;
    int cnt = *counter; if (cnt > CAP) cnt = CAP;

    for (int base = blockIdx.x * 8; base < cnt; base += gridDim.x * 8) {
        if (tid < 128) {   // stage 8 rows (tail-clamped; dups computed, not written)
            int r  = tid >> 4, q = tid & 15;
            int li = base + r; if (li >= cnt) li = cnt - 1;
            int row = list[li];
            float4 v = reinterpret_cast<const float4*>(x + (size_t)row * DIM)[q];
            *reinterpret_cast<float4*>(&xs[r][q * 4]) = v;
        }
        __syncthreads();
        if (tid < 8) {   // x_sq: numpy pairwise structure (bitwise-same values)
            float r8[8];
#pragma unroll
            for (int g = 0; g < 8; ++g)
#pragma unroll
                for (int j = 0; j < 8; ++j) {
                    float xv = xs[tid][8 * g + j];
                    float sq = xv * xv;
                    if (g == 0) r8[j] = sq; else r8[j] += sq;
                }
            xsq_s[tid] = ((r8[0] + r8[1]) + (r8[2] + r8[3]))
                       + ((r8[4] + r8[5]) + (r8[6] + r8[7]));
        }
        __syncthreads();

        float bmv[8]; int bmi[8];
#pragma unroll
        for (int r = 0; r < 8; ++r) { bmv[r] = INFINITY; bmi[r] = 0; }

#pragma clang loop unroll(disable)
        for (int cc = 0; cc < 4; ++cc) {
            const int c = cc * 256 + tid;             // in-thread ascending
            float dot[8];
#pragma unroll
            for (int r = 0; r < 8; ++r) dot[r] = 0.0f;
#pragma clang loop unroll(disable)
            for (int q = 0; q < 16; ++q) {
                const float4 cv = cbt4[q * 1024 + c]; // ONE codebook quad live
#pragma unroll
                for (int r = 0; r < 8; ++r) {
                    float4 xv = *reinterpret_cast<const float4*>(&xs[r][q * 4]);
                    dot[r] = __builtin_fmaf(cv.x, xv.x, dot[r]);
                    dot[r] = __builtin_fmaf(cv.y, xv.y, dot[r]);
                    dot[r] = __builtin_fmaf(cv.z, xv.z, dot[r]);
                    dot[r] = __builtin_fmaf(cv.w, xv.w, dot[r]);
                }
            }
            const float cs = csq[c];
#pragma unroll
            for (int r = 0; r < 8; ++r) {
                float dist = (xsq_s[r] - 2.0f * dot[r]) + cs;
                if (dist < bmv[r]) { bmv[r] = dist; bmi[r] = c; }
            }
        }

        // per-row reduce: wave lex-min, then cross-wave via LDS
#pragma unroll
        for (int r = 0; r < 8; ++r) {
#pragma unroll
            for (int m = 1; m <= 32; m <<= 1) {
                float ov = __shfl_xor(bmv[r], m, 64);
                int   oi = __shfl_xor(bmi[r], m, 64);
                if (ov < bmv[r] || (ov == bmv[r] && oi < bmi[r])) {
                    bmv[r] = ov; bmi[r] = oi;
                }
            }
            if (lane == 0) { bv[w][r] = bmv[r]; bix[w][r] = bmi[r]; }
        }
        __syncthreads();
        if (tid < 8) {
            float v = bv[0][tid]; int ix = bix[0][tid];
#pragma unroll
            for (int k = 1; k < 4; ++k)
                if (bv[k][tid] < v || (bv[k][tid] == v && bix[k][tid] < ix)) {
                    v = bv[k][tid]; ix = bix[k][tid];
                }
            int li = base + tid;
            if (li < cnt) zout[list[li]] = (float)ix;
        }
        __syncthreads();   // xs/bv reused next batch
    }
}

// ---------------------------------------------------------------- epilogue
__global__ __launch_bounds__(256) void epilogue_kernel(
        const float* __restrict__ x, const float* __restrict__ cb,
        const float* __restrict__ zf, float* __restrict__ qout,
        double* __restrict__ partial) {
#pragma clang fp contract(off)
    const int gid = blockIdx.x * 256 + threadIdx.x;
    const int row = gid >> 2;
    const int d0  = (gid & 3) * 16;
    const float4* xr = reinterpret_cast<const float4*>(x + (size_t)row * DIM + d0);
    const int z = (int)zf[row];
    const float4* qr = reinterpret_cast<const float4*>(cb + (size_t)z * DIM + d0);
    float4* op = reinterpret_cast<float4*>(qout + (size_t)row * DIM + d0);

    float lf = 0.0f;
#pragma unroll
    for (int q = 0; q < 4; ++q) {
        float4 xv = xr[q];
        float4 qv = qr[q];
        float da = qv.x - xv.x, db = qv.y - xv.y, dc = qv.z - xv.z, dd = qv.w - xv.w;
        float4 o;
        o.x = xv.x + da; o.y = xv.y + db; o.z = xv.z + dc; o.w = xv.w + dd;
        op[q] = o;
        lf += da * da; lf += db * db; lf += dc * dc; lf += dd * dd;
    }
    double lsum = (double)lf;
#pragma unroll
    for (int s = 32; s >= 1; s >>= 1) lsum += __shfl_down(lsum, s, 64);
    __shared__ double wsum[4];
    const int lane = threadIdx.x & 63, wid = threadIdx.x >> 6;
    if (lane == 0) wsum[wid] = lsum;
    __syncthreads();
    if (threadIdx.x == 0)
        partial[blockIdx.x] = (wsum[0] + wsum[1]) + (wsum[2] + wsum[3]);
}

__global__ void finalize_kernel(const double* __restrict__ partial,
                                float* __restrict__ losses) {
    double s = 0.0;
    int lane = threadIdx.x;
    for (int i = lane; i < 4096; i += 64) s += partial[i];
#pragma unroll
    for (int sh = 32; sh >= 1; sh >>= 1) s += __shfl_down(s, sh, 64);
    if (lane == 0) {
        float v = (float)(s / 16777216.0);
        losses[0] = v;
        losses[1] = v;
    }
}

extern "C" void kernel_launch(void* const* d_in, const int* in_sizes, int n_in,
                              void* d_out, int out_size, void* d_ws, size_t ws_size,
                              hipStream_t stream) {
    const float* x  = (const float*)d_in[0];
    const float* cb = (const float*)d_in[1];
    float* out    = (float*)d_out;
    float* zout   = out;
    float* qout   = out + NROWS;
    float* losses = out + NROWS + (size_t)NROWS * DIM;

    float*          csq     = (float*)((char*)d_ws + CSQ_OFF);
    float*          cspre   = (float*)((char*)d_ws + CSPRE_OFF);
    unsigned short* csplit  = (unsigned short*)((char*)d_ws + CSPLIT_OFF);
    int*            counter = (int*)((char*)d_ws + CTR_OFF);
    int*            list    = (int*)((char*)d_ws + LIST_OFF);
    double*         partial = (double*)((char*)d_ws + PART_OFF);

    // cbT4 (256 KB) lives in the qout region of d_out: written by prep, read by
    // rescore, fully overwritten by the epilogue afterwards (R6-proven).
    float4* cbt4 = (float4*)qout;

    prep_kernel<<<16, 64, 0, stream>>>(cb, csq, cspre, csplit, cbt4, counter);
    vq_mfma_kernel<<<NROWS / 256, 256, 0, stream>>>(x, csplit, cspre, zout, counter, list);
    rescore_kernel<<<1024, 256, 0, stream>>>(x, cbt4, csq, counter, list, zout);
    epilogue_kernel<<<(NROWS * 4) / 256, 256, 0, stream>>>(x, cb, zout, qout, partial);
    finalize_kernel<<<1, 64, 0, stream>>>(partial, losses);
}